// Round 1
// baseline (126.651 us; speedup 1.0000x reference)
//
#include <hip/hip_runtime.h>

// Problem constants (fixed by setup_inputs)
#define T_TOTAL 8192
#define NB      64
#define NF      26
#define NPOP    3
#define NCHAIN  (NPOP * NF)   // 78
#define NC      32            // chunks over T
#define TC      (T_TOTAL / NC) // 256 timesteps per block
#define TS      128            // sub-tile (== blockDim)
#define WARM    64             // speculative warm-up steps

// One LIF step, matching reference rounding exactly:
//   v_dec = v + (DT*tau) * (0 - v + x)   [separate mul + add, no fma]
//   z     = v_dec > vth
//   v     = z ? 0 : v_dec
__device__ __forceinline__ unsigned lif_step(float& v, float a, float th, float x) {
    float t1 = x - v;                              // == (0 - v) + x bitwise
    float vd = __fadd_rn(v, __fmul_rn(a, t1));     // block fp contraction
    unsigned z = (vd > th) ? 1u : 0u;
    v = z ? 0.0f : vd;
    return z;
}

__global__ __launch_bounds__(TS, 8)
void snn_fused_kernel(const float* __restrict__ x,      // [B][F][T]
                      const float* __restrict__ tau,    // [3]
                      const float* __restrict__ vth,    // [3]
                      const float* __restrict__ conv_w, // [3]
                      const float* __restrict__ conv_b, // [1]
                      const float* __restrict__ w1,     // [12][26]
                      const float* __restrict__ b1,     // [12]
                      const float* __restrict__ w2,     // [4][12]
                      const float* __restrict__ b2,     // [4]
                      const float* __restrict__ w3,     // [2][4]
                      const float* __restrict__ b3,     // [2]
                      float* __restrict__ out)          // [B][2][T]
{
    const int chunk = blockIdx.x;
    const int b     = blockIdx.y;
    const int tid   = threadIdx.x;

    __shared__ float sM[2][NF];          // combined matrix W3@W2@W1
    __shared__ float sC0[NCHAIN];        // per-chain coeff for output 0
    __shared__ float sC1[NCHAIN];        // per-chain coeff for output 1
    __shared__ float sConst[2];          // combined bias (incl. conv_b path)
    __shared__ unsigned sZ[NCHAIN][TS / 32];

    // ---- one-time combined-coefficient setup (linear head collapse) ----
    if (tid < 2 * NF) {
        int o = tid / NF, f = tid % NF;
        float m = 0.0f;
        for (int j = 0; j < 4; ++j) {
            float a = 0.0f;
            for (int k = 0; k < 12; ++k) a += w2[j * 12 + k] * w1[k * NF + f];
            m += w3[o * 4 + j] * a;
        }
        sM[o][f] = m;
    }
    __syncthreads();
    if (tid < NCHAIN) {
        int c = tid / NF, f = tid % NF;
        sC0[tid] = sM[0][f] * conv_w[c];
        sC1[tid] = sM[1][f] * conv_w[c];
    }
    if (tid == 0) {
        float ab[4];
        for (int j = 0; j < 4; ++j) {
            float a = b2[j];
            for (int k = 0; k < 12; ++k) a += w2[j * 12 + k] * b1[k];
            ab[j] = a;
        }
        for (int o = 0; o < 2; ++o) {
            float s = b3[o];
            for (int j = 0; j < 4; ++j) s += w3[o * 4 + j] * ab[j];
            float msum = 0.0f;
            for (int f = 0; f < NF; ++f) msum += sM[o][f];
            sConst[o] = s + conv_b[0] * msum;
        }
    }

    // ---- chain setup ----
    const int t0 = chunk * TC;
    float v = 0.0f, a_ = 0.0f, th = 0.0f;
    const float* xp = nullptr;
    if (tid < NCHAIN) {
        int c = tid / NF, f = tid % NF;
        a_ = __fmul_rn(0.001f, tau[c]);   // DT * tau in f32 (matches ref bits)
        th = vth[c];
        xp = x + ((size_t)b * NF + f) * T_TOTAL;

        // Speculative warm-up: start v=0 at t0-WARM; first spike => bit-exact.
        if (chunk > 0) {
            const float4* xw = (const float4*)(xp + t0 - WARM);
            #pragma unroll
            for (int q = 0; q < WARM / 4; ++q) {
                float4 xv = xw[q];
                lif_step(v, a_, th, xv.x);
                lif_step(v, a_, th, xv.y);
                lif_step(v, a_, th, xv.z);
                lif_step(v, a_, th, xv.w);
            }
        }
    }

    // ---- main loop over sub-tiles of TS timesteps ----
    const int word = tid >> 5;
    const int bit  = tid & 31;
    #pragma unroll
    for (int s = 0; s < TC / TS; ++s) {
        // Phase A: 78 chain threads advance TS steps, pack z bits into LDS
        if (tid < NCHAIN) {
            const float4* xw = (const float4*)(xp + t0 + s * TS);
            #pragma unroll
            for (int w = 0; w < TS / 32; ++w) {
                unsigned bw = 0;
                #pragma unroll
                for (int q = 0; q < 8; ++q) {
                    float4 xv = xw[w * 8 + q];
                    bw |= lif_step(v, a_, th, xv.x) << (q * 4 + 0);
                    bw |= lif_step(v, a_, th, xv.y) << (q * 4 + 1);
                    bw |= lif_step(v, a_, th, xv.z) << (q * 4 + 2);
                    bw |= lif_step(v, a_, th, xv.w) << (q * 4 + 3);
                }
                sZ[tid][w] = bw;
            }
        }
        __syncthreads();

        // Phase B: all 128 threads, one timestep each — weighted popcount
        {
            float acc0 = sConst[0];
            float acc1 = sConst[1];
            #pragma unroll
            for (int ch = 0; ch < NCHAIN; ++ch) {
                unsigned wv = sZ[ch][word];
                if ((wv >> bit) & 1u) { acc0 += sC0[ch]; acc1 += sC1[ch]; }
            }
            const int t = t0 + s * TS + tid;
            out[((size_t)b * 2 + 0) * T_TOTAL + t] = acc0;
            out[((size_t)b * 2 + 1) * T_TOTAL + t] = acc1;
        }
        __syncthreads();
    }
}

extern "C" void kernel_launch(void* const* d_in, const int* in_sizes, int n_in,
                              void* d_out, int out_size, void* d_ws, size_t ws_size,
                              hipStream_t stream) {
    const float* x      = (const float*)d_in[0];
    const float* tau    = (const float*)d_in[1];
    const float* vth    = (const float*)d_in[2];
    const float* conv_w = (const float*)d_in[3];
    const float* conv_b = (const float*)d_in[4];
    const float* w1     = (const float*)d_in[5];
    const float* b1     = (const float*)d_in[6];
    const float* w2     = (const float*)d_in[7];
    const float* b2     = (const float*)d_in[8];
    const float* w3     = (const float*)d_in[9];
    const float* b3     = (const float*)d_in[10];
    float* out = (float*)d_out;

    dim3 grid(NC, NB);
    snn_fused_kernel<<<grid, TS, 0, stream>>>(x, tau, vth, conv_w, conv_b,
                                              w1, b1, w2, b2, w3, b3, out);
}

// Round 2
// 116.488 us; speedup vs baseline: 1.0873x; 1.0873x over previous
//
#include <hip/hip_runtime.h>

// Problem constants (fixed by setup_inputs)
#define T_TOTAL 8192
#define NB      64
#define NF      26
#define NPOP    3
#define NCHAIN  (NPOP * NF)    // 78 chains per (b)
#define TCS     64             // timesteps per sub-chunk (serial scan length)
#define CPB     4              // sub-chunks per block
#define TB      (TCS * CPB)    // 256 timesteps covered per block
#define WARM    16             // speculative warm-up steps (reads staged LDS only)
#define NSCAN   (NCHAIN * CPB) // 312 scan threads
#define BLOCK   320            // 5 waves
#define ROWW    272            // staged words per feature row = TB + WARM
#define RSTRIDE 273            // +1 pad: banks = (17*f + j) % 32, conflict-free

// One LIF step, matching reference rounding exactly:
//   v_dec = v + (DT*tau)*((0 - v) + x); z = v_dec > vth; v = z ? 0 : v_dec
__device__ __forceinline__ unsigned lif_step(float& v, float a, float th, float x) {
    float t1 = x - v;                           // bitwise == (0 - v) + x
    float vd = __fadd_rn(v, __fmul_rn(a, t1));  // block fp contraction
    unsigned z = (vd > th) ? 1u : 0u;
    v = z ? 0.0f : vd;
    return z;
}

__global__ __launch_bounds__(BLOCK, 4)
void snn_fused_kernel(const float* __restrict__ x,      // [B][F][T]
                      const float* __restrict__ tau,    // [3]
                      const float* __restrict__ vth,    // [3]
                      const float* __restrict__ conv_w, // [3]
                      const float* __restrict__ conv_b, // [1]
                      const float* __restrict__ w1,     // [12][26]
                      const float* __restrict__ b1,     // [12]
                      const float* __restrict__ w2,     // [4][12]
                      const float* __restrict__ b2,     // [4]
                      const float* __restrict__ w3,     // [2][4]
                      const float* __restrict__ b3,     // [2]
                      float* __restrict__ out)          // [B][2][T]
{
    const int blk = blockIdx.x;       // t-block: covers [tb, tb+256)
    const int b   = blockIdx.y;
    const int tid = threadIdx.x;
    const int tb  = blk * TB;

    __shared__ float    sX[NF * RSTRIDE];      // staged x rows [f][j], j = t - tb + 16
    __shared__ unsigned sZ[2 * CPB][NCHAIN];   // z bits, word-major then chain
    __shared__ float2   sC01[NCHAIN];          // per-chain coeffs for outputs 0,1
    __shared__ float    sMr[2][NF];            // raw combined matrix (for bias calc)
    __shared__ float    sConst[2];             // combined constant term

    // ---- per-chain combined coefficients (linear head collapsed) ----
    if (tid < NCHAIN) {
        const int c = tid / NF, f = tid % NF;
        float m0 = 0.0f, m1 = 0.0f;
        #pragma unroll
        for (int j = 0; j < 4; ++j) {
            float a = 0.0f;
            #pragma unroll
            for (int k = 0; k < 12; ++k) a += w2[j * 12 + k] * w1[k * NF + f];
            m0 += w3[j] * a;
            m1 += w3[4 + j] * a;
        }
        const float cw = conv_w[c];
        sC01[tid] = make_float2(m0 * cw, m1 * cw);
        if (c == 0) { sMr[0][f] = m0; sMr[1][f] = m1; }
    }

    // ---- coalesced global -> LDS staging (b32: stride-1 lanes, no conflicts) ----
    {
        const float* xb = x + (size_t)b * NF * T_TOTAL;
        for (int i = tid; i < NF * ROWW; i += BLOCK) {
            const int f = i / ROWW;
            const int j = i - f * ROWW;
            int t = tb - WARM + j;
            t = (t < 0) ? 0 : t;             // clamp for blk==0 (garbage, unused)
            sX[f * RSTRIDE + j] = xb[f * T_TOTAL + t];
        }
    }
    __syncthreads();

    // ---- scan phase: 312 threads, each (chain, sub-chunk) ----
    if (tid < NSCAN) {
        const int ch = tid % NCHAIN;         // k-major lane order: 2-way max conflicts
        const int k  = tid / NCHAIN;
        const int c  = ch / NF, f = ch % NF;
        const float a_ = __fmul_rn(0.001f, tau[c]);
        const float th = vth[c];
        const float* row = sX + f * RSTRIDE;
        const int j0 = WARM + k * TCS;
        float v = 0.0f;
        if (!(tb == 0 && k == 0)) {          // speculative warm-up from staged LDS
            #pragma unroll
            for (int q = 0; q < WARM; ++q) lif_step(v, a_, th, row[j0 - WARM + q]);
        }
        #pragma unroll
        for (int w = 0; w < 2; ++w) {
            unsigned bw = 0;
            #pragma unroll
            for (int q = 0; q < 32; ++q)
                bw |= lif_step(v, a_, th, row[j0 + w * 32 + q]) << q;
            sZ[k * 2 + w][ch] = bw;          // stride-1 across lanes
        }
    } else if (tid == NSCAN) {
        // idle-during-scan thread computes the constant term (reads sMr, pre-barrier)
        float ab[4];
        #pragma unroll
        for (int j = 0; j < 4; ++j) {
            float a = b2[j];
            #pragma unroll
            for (int k = 0; k < 12; ++k) a += w2[j * 12 + k] * b1[k];
            ab[j] = a;
        }
        #pragma unroll
        for (int o = 0; o < 2; ++o) {
            float s = b3[o];
            #pragma unroll
            for (int j = 0; j < 4; ++j) s += w3[o * 4 + j] * ab[j];
            float msum = 0.0f;
            for (int f = 0; f < NF; ++f) msum += sMr[o][f];
            sConst[o] = s + conv_b[0] * msum;
        }
    }
    __syncthreads();

    // ---- reduce phase: 256 threads, one timestep each ----
    if (tid < TB) {
        const int wrd = tid >> 5;
        const int bit = tid & 31;
        float acc0 = sConst[0];
        float acc1 = sConst[1];
        for (int ch = 0; ch < NCHAIN; ++ch) {
            const unsigned wv = sZ[wrd][ch];           // broadcast read
            const float s = (float)((wv >> bit) & 1u);
            const float2 c01 = sC01[ch];               // broadcast read
            acc0 = fmaf(s, c01.x, acc0);
            acc1 = fmaf(s, c01.y, acc1);
        }
        const size_t t = (size_t)tb + tid;
        out[((size_t)b * 2 + 0) * T_TOTAL + t] = acc0;
        out[((size_t)b * 2 + 1) * T_TOTAL + t] = acc1;
    }
}

extern "C" void kernel_launch(void* const* d_in, const int* in_sizes, int n_in,
                              void* d_out, int out_size, void* d_ws, size_t ws_size,
                              hipStream_t stream) {
    const float* x      = (const float*)d_in[0];
    const float* tau    = (const float*)d_in[1];
    const float* vth    = (const float*)d_in[2];
    const float* conv_w = (const float*)d_in[3];
    const float* conv_b = (const float*)d_in[4];
    const float* w1     = (const float*)d_in[5];
    const float* b1     = (const float*)d_in[6];
    const float* w2     = (const float*)d_in[7];
    const float* b2     = (const float*)d_in[8];
    const float* w3     = (const float*)d_in[9];
    const float* b3     = (const float*)d_in[10];
    float* out = (float*)d_out;

    dim3 grid(T_TOTAL / TB, NB);   // (32, 64)
    snn_fused_kernel<<<grid, BLOCK, 0, stream>>>(x, tau, vth, conv_w, conv_b,
                                                 w1, b1, w2, b2, w3, b3, out);
}